// Round 11
// baseline (1239.320 us; speedup 1.0000x reference)
//
#include <hip/hip_runtime.h>
#include <hip/hip_cooperative_groups.h>
#include <math.h>

namespace cg = cooperative_groups;

#define E 192
#define DI 384
#define S 16
#define R 12
#define DEPTH 4
#define P 400
#define NC 20
#define BATCH 32
#define L 401
#define NTOK (BATCH * L)   // 12832
#define CH 32
#define NCH 13             // ceil(401/32)

using short8 = __attribute__((ext_vector_type(8))) short;
using float4v = __attribute__((ext_vector_type(4))) float;

__device__ __forceinline__ float siluf(float x) {
    return x / (1.f + __expf(-x));
}
__device__ __forceinline__ float softplusf(float x) {
    return (x > 20.f) ? x : log1pf(__expf(x));
}
// f32 -> bf16 round-to-nearest-even (bit-level; no __hip_bfloat16 dep)
__device__ __forceinline__ unsigned short f2bf(float x) {
    unsigned int u = __float_as_uint(x);
    unsigned int r = 0x7fffu + ((u >> 16) & 1u);
    return (unsigned short)((u + r) >> 16);
}
__device__ __forceinline__ float bf2f(unsigned short v) {
    return __uint_as_float(((unsigned int)v) << 16);
}

// ---------------------------------------------------------------------------
// K0: patch embed + pos + depthwise conv3 + cls token  -> resid[b,l,e]
// ---------------------------------------------------------------------------
__global__ void k_embed(const float* __restrict__ imgs, const float* __restrict__ patch_w,
                        const float* __restrict__ patch_b, const float* __restrict__ cls_token,
                        const float* __restrict__ pos_embed, const float* __restrict__ cnn_w,
                        const float* __restrict__ cnn_b, float* __restrict__ resid) {
    int idx = blockIdx.x * blockDim.x + threadIdx.x;
    if (idx >= NTOK * E) return;
    int e = idx % E;
    int bl = idx / E;
    int l = bl % L;
    int b = bl / L;
    float out;
    if (l == P) {
        out = cls_token[e] + pos_embed[(size_t)P * E + e];
    } else {
        float w0 = patch_w[e * 4 + 0], w1 = patch_w[e * 4 + 1];
        float w2 = patch_w[e * 4 + 2], w3 = patch_w[e * 4 + 3];
        float pb = patch_b[e];
        const float* ib = imgs + (size_t)b * 1600;
        auto xe = [&](int ll) -> float {
            const float* ip = ib + ll * 4;
            return ip[0] * w0 + ip[1] * w1 + ip[2] * w2 + ip[3] * w3 + pb +
                   pos_embed[(size_t)ll * E + e];
        };
        float c0 = cnn_w[e * 3 + 0], c1 = cnn_w[e * 3 + 1], c2 = cnn_w[e * 3 + 2];
        float acc = cnn_b[e] + xe(l) * c1;
        if (l > 0) acc += xe(l - 1) * c0;
        if (l < P - 1) acc += xe(l + 1) * c2;
        out = acc;
    }
    resid[idx] = out;
}

// ---------------------------------------------------------------------------
// K1: hn = rmsnorm(resid)*w -> bf16 (read-only resid; accumulate is in
// out_proj's EPI=2 epilogue).
// ---------------------------------------------------------------------------
__global__ void k_rmsnorm(const float* __restrict__ resid, unsigned short* __restrict__ hn,
                          const float* __restrict__ w) {
    int wave = blockIdx.x * (blockDim.x >> 6) + (threadIdx.x >> 6);
    int lane = threadIdx.x & 63;
    if (wave >= NTOK) return;
    size_t base = (size_t)wave * E;
    float v[3];
    float ss = 0.f;
#pragma unroll
    for (int j = 0; j < 3; j++) {
        int e = lane + j * 64;
        float r = resid[base + e];
        v[j] = r;
        ss += r * r;
    }
#pragma unroll
    for (int off = 32; off > 0; off >>= 1) ss += __shfl_xor(ss, off, 64);
    float scale = rsqrtf(ss * (1.f / (float)E) + 1e-5f);
#pragma unroll
    for (int j = 0; j < 3; j++) {
        int e = lane + j * 64;
        hn[base + e] = f2bf(v[j] * scale * w[e]);
    }
}

// ---------------------------------------------------------------------------
// K_prep: weight bf16 conversions + transposed negA ([layer][n][d]) +
// transposed dt weights ([layer][r][d]) in one kernel.
// ---------------------------------------------------------------------------
__global__ void k_prep(const float* __restrict__ in_proj_w, const float* __restrict__ x_proj_w,
                       const float* __restrict__ out_proj_w, const float* __restrict__ A_log,
                       const float* __restrict__ dt_proj_w,
                       unsigned short* __restrict__ w_in, unsigned short* __restrict__ w_x,
                       unsigned short* __restrict__ w_out, float* __restrict__ negA,
                       float* __restrict__ dtw_t) {
    const int n1 = DEPTH * 2 * DI * E;
    const int n2 = DEPTH * 44 * DI;
    const int n3 = DEPTH * E * DI;
    const int n4 = DEPTH * DI * S;
    const int n5 = DEPTH * DI * R;
    int idx = blockIdx.x * blockDim.x + threadIdx.x;
    if (idx < n1) {
        w_in[idx] = f2bf(in_proj_w[idx]);
    } else if (idx < n1 + n2) {
        int i = idx - n1;
        w_x[i] = f2bf(x_proj_w[i]);
    } else if (idx < n1 + n2 + n3) {
        int i = idx - n1 - n2;
        w_out[i] = f2bf(out_proj_w[i]);
    } else if (idx < n1 + n2 + n3 + n4) {
        int i = idx - n1 - n2 - n3;
        int layer = i / (DI * S);
        int rem = i % (DI * S);
        int n = rem / DI;
        int d = rem % DI;
        negA[i] = -__expf(A_log[(size_t)layer * DI * S + d * S + n]);
    } else if (idx < n1 + n2 + n3 + n4 + n5) {
        int i = idx - n1 - n2 - n3 - n4;
        int layer = i / (DI * R);
        int rem = i % (DI * R);
        int r = rem / DI;
        int d = rem % DI;
        dtw_t[i] = dt_proj_w[(size_t)layer * DI * R + d * R + r];
    }
}

// K_flag: per (layer,d): is a_n == (n+1)*a_0 for all n? -> pow-chain eligible
__global__ void k_flag(const float* __restrict__ negA, int* __restrict__ flag) {
    int idx = blockIdx.x * blockDim.x + threadIdx.x;
    if (idx >= DEPTH * DI) return;
    int layer = idx / DI;
    int d = idx % DI;
    const float* base = negA + (size_t)layer * DI * S;
    float a0 = base[d];
    bool ok = true;
#pragma unroll
    for (int n = 1; n < S; n++) {
        float an = base[n * DI + d];
        ok = ok && (fabsf(an - (float)(n + 1) * a0) <= 1e-5f * fabsf(an));
    }
    flag[idx] = ok ? 1 : 0;
}

// ---------------------------------------------------------------------------
// K2: bf16 MFMA GEMM  C = A[M,K](bf16) * W[N,K](bf16)^T
// block 256 (4 waves, 2x2 over (M,N)), tile BM x BN, K-tile BK.
// BK is a free parameter: accumulation order is monotonic in K for any BK ->
// results BIT-IDENTICAL across BK (verified R7: absmax unchanged).
// EPI=0: C[M,N] f32.
// EPI=1 (in_proj split): n<DI -> XMbf16[m*DI+n] (xm), n>=DI -> Zbf16 (z gate).
// EPI=2: C[M,N] += acc  (out_proj fused residual accumulate)
// ---------------------------------------------------------------------------
template <int BM, int BN, int BK, int EPI>
__global__ __launch_bounds__(256) void k_gemm_bf16(const unsigned short* __restrict__ A,
                                                   const unsigned short* __restrict__ W,
                                                   float* __restrict__ C,
                                                   unsigned short* __restrict__ XM,
                                                   unsigned short* __restrict__ Z,
                                                   int M, int N, int K) {
    constexpr int PADK = BK + 8;
    constexpr int MT = BM / 32, NT = BN / 32;
    __shared__ unsigned short As[BM][PADK];
    __shared__ unsigned short Bs[BN][PADK];
    int tid = threadIdx.x;
    int m0 = blockIdx.y * BM, n0 = blockIdx.x * BN;
    int wave = tid >> 6, lane = tid & 63;
    int row16 = lane & 15, quad = lane >> 4;
    int wm0 = (wave >> 1) * (BM / 2), wn0 = (wave & 1) * (BN / 2);

    float4v acc[MT][NT];
#pragma unroll
    for (int i = 0; i < MT; i++)
#pragma unroll
        for (int j = 0; j < NT; j++) acc[i][j] = (float4v){0.f, 0.f, 0.f, 0.f};

    for (int k0 = 0; k0 < K; k0 += BK) {
#pragma unroll
        for (int idx = tid * 8; idx < BM * BK; idx += 256 * 8) {
            int row = idx / BK, col = idx % BK;
            int gm = m0 + row;
            short8 v;
            if (gm < M)
                v = *(const short8*)&A[(size_t)gm * K + k0 + col];
            else
                v = (short8)0;
            *(short8*)&As[row][col] = v;
        }
#pragma unroll
        for (int idx = tid * 8; idx < BN * BK; idx += 256 * 8) {
            int row = idx / BK, col = idx % BK;
            int gn = n0 + row;
            short8 v;
            if (gn < N)
                v = *(const short8*)&W[(size_t)gn * K + k0 + col];
            else
                v = (short8)0;
            *(short8*)&Bs[row][col] = v;
        }
        __syncthreads();
#pragma unroll
        for (int kk = 0; kk < BK; kk += 32) {
            int koff = kk + quad * 8;
            short8 af[MT], bfr[NT];
#pragma unroll
            for (int i = 0; i < MT; i++)
                af[i] = *(const short8*)&As[wm0 + i * 16 + row16][koff];
#pragma unroll
            for (int j = 0; j < NT; j++)
                bfr[j] = *(const short8*)&Bs[wn0 + j * 16 + row16][koff];
#pragma unroll
            for (int i = 0; i < MT; i++)
#pragma unroll
                for (int j = 0; j < NT; j++)
                    acc[i][j] = __builtin_amdgcn_mfma_f32_16x16x32_bf16(af[i], bfr[j],
                                                                        acc[i][j], 0, 0, 0);
        }
        __syncthreads();
    }
#pragma unroll
    for (int i = 0; i < MT; i++) {
#pragma unroll
        for (int j = 0; j < NT; j++) {
#pragma unroll
            for (int r = 0; r < 4; r++) {
                int m = m0 + wm0 + i * 16 + quad * 4 + r;
                int n = n0 + wn0 + j * 16 + row16;
                if (m >= M || n >= N) continue;
                float v = acc[i][j][r];
                if (EPI == 0) {
                    C[(size_t)m * N + n] = v;
                } else if (EPI == 1) {
                    if (n < DI)
                        XM[(size_t)m * DI + n] = f2bf(v);
                    else
                        Z[(size_t)m * DI + (n - DI)] = f2bf(v);
                } else {
                    C[(size_t)m * N + n] += v;  // residual accumulate
                }
            }
        }
    }
}

// ---------------------------------------------------------------------------
// K3: causal depthwise conv4 + SiLU over xm(bf16) -> xc_bf (bf16)
// (kept as a streaming kernel ON PURPOSE; every fusion/replacement attempt
//  of the conv/x_proj/dt slot regressed: R2 +36, R3 +85, R5 +165, R6 +130.)
// ---------------------------------------------------------------------------
__global__ void k_conv(const unsigned short* __restrict__ xm_bf, const float* __restrict__ cw,
                       const float* __restrict__ cb, unsigned short* __restrict__ xc_bf) {
    int idx = blockIdx.x * blockDim.x + threadIdx.x;
    if (idx >= NTOK * DI) return;
    int d = idx % DI;
    int bl = idx / DI;
    int l = bl % L;
    int b = bl / L;
    const unsigned short* base = xm_bf + (size_t)b * L * DI + d;
    float acc = cb[d];
#pragma unroll
    for (int k = 0; k < 4; k++) {
        int ll = l - 3 + k;
        if (ll >= 0) acc += bf2f(base[(size_t)ll * DI]) * cw[d * 4 + k];
    }
    xc_bf[idx] = f2bf(siluf(acc));
}

// ---------------------------------------------------------------------------
// K_dtpre: one block per token. dt = softplus(xdb_row . dtw_t + dtb) -> f32.
// ---------------------------------------------------------------------------
__global__ __launch_bounds__(384) void k_dtpre(
        const float* __restrict__ xdb, const float* __restrict__ dtw_t,
        const float* __restrict__ dtb, float* __restrict__ dtbuf) {
    int tok = blockIdx.x;
    int d = threadIdx.x;
    const float* xr = xdb + (size_t)tok * 44;
    float acc = dtb[d];
#pragma unroll
    for (int r = 0; r < R; r++) acc += xr[r] * dtw_t[r * DI + d];
    dtbuf[(size_t)tok * DI + d] = softplusf(acc);
}

// ---------------------------------------------------------------------------
// K_scan_fused (R11): scanA + scanB + fixup in ONE cooperative kernel.
// grid (NCH, BATCH) x 384, hipLaunchCooperativeKernel, 2x grid.sync().
//   Phase 1: exact scanA loop; y kept in LDS ysm[CH][DI] (no ydt buffer!);
//            writes hend + dtlast (chunk-final dtcum, == old ydt[tlast].y).
//   Phase 2: ch==0 blocks fold prefixes for their b in EXACT scanB order
//            (no per-block redundant fold -- that was R8's 61MB regression).
//   Phase 3: each block loads its h0 ONCE (hinit re-read 315MB->10MB/layer),
//            recomputes per-token dtcum by the bit-identical sequential
//            re-sum of dtbuf, applies corr + silu gate, writes y_bf.
// Removes per layer: ydt write+read (79MB), 2 launches, per-token h0 loads.
// Occupancy audit for co-residency: LDS 49KB + <=128 VGPR
// (__launch_bounds__(384,3)) -> 2 blocks/CU -> 512 >= 416 blocks. [R11]
// ---------------------------------------------------------------------------
template <bool LAST>
__global__ __launch_bounds__(384, 3) void k_scan_fused(
        const unsigned short* __restrict__ xc_bf, const float* __restrict__ xdb,
        const float* __restrict__ dtbuf, const float* __restrict__ negA_l,
        const int* __restrict__ flag_l, const float* __restrict__ Dskip,
        const unsigned short* __restrict__ z_bf,
        float* __restrict__ hend, float* __restrict__ dtlast,
        float* __restrict__ hinit, unsigned short* __restrict__ y_out) {
    __shared__ float ysm[CH][DI];   // 49152 B
    int d = threadIdx.x;
    int ch = blockIdx.x;
    int b = blockIdx.y;
    int t0 = ch * CH;
    int t1 = min(t0 + CH, L);
    bool fast = __all(flag_l[d] != 0);
    float a0 = negA_l[d];
    float a[S];
    if (!fast) {
#pragma unroll
        for (int n = 0; n < S; n++) a[n] = negA_l[n * DI + d];
    }
    float dsk = Dskip[d];

    // ---- phase 1: chunk-local scan (exact scanA order), y -> LDS ----
    {
        float h[S] = {};
        float dts = 0.f;
        size_t tok0 = (size_t)b * L + t0;
        float dt_nx = dtbuf[tok0 * DI + d];
        float u_nx = bf2f(xc_bf[tok0 * DI + d]);
        float e1_nx = __expf(a0 * dt_nx);
        for (int t = t0; t < t1; t++) {
            size_t tok = (size_t)b * L + t;
            float dtv = dt_nx, e1v = e1_nx, uu = u_nx;
            if (t + 1 < t1) {  // prefetch + exp for next step, hidden by h-chain
                dt_nx = dtbuf[(tok + 1) * DI + d];
                u_nx = bf2f(xc_bf[(tok + 1) * DI + d]);
                e1_nx = __expf(a0 * dt_nx);
            }
            const float* row = xdb + tok * 44;   // block-uniform -> s_loads
            dts += dtv;
            float dtu = dtv * uu;
            float y = uu * dsk;
            if (fast) {
                float p = e1v;
#pragma unroll
                for (int n = 0; n < S; n++) {
                    h[n] = p * h[n] + dtu * row[R + n];
                    y += h[n] * row[R + S + n];
                    p *= e1v;
                }
            } else {
#pragma unroll
                for (int n = 0; n < S; n++) {
                    float dA = __expf(dtv * a[n]);
                    h[n] = dA * h[n] + dtu * row[R + n];
                    y += h[n] * row[R + S + n];
                }
            }
            ysm[t - t0][d] = y;
        }
        float* he = hend + ((size_t)(b * NCH + ch) * S) * DI + d;
#pragma unroll
        for (int n = 0; n < S; n++) he[n * DI] = h[n];
        dtlast[(size_t)(b * NCH + ch) * DI + d] = dts;
    }

    cg::this_grid().sync();

    // ---- phase 2: serial prefix fold by ch==0 blocks (exact scanB order) ----
    if (ch == 0) {
        float hh[S] = {};
        for (int c = 0; c < NCH; c++) {
            size_t o = ((size_t)(b * NCH + c) * S) * DI + d;
#pragma unroll
            for (int n = 0; n < S; n++) hinit[o + n * DI] = hh[n];
            float dl = dtlast[(size_t)(b * NCH + c) * DI + d];
            if (fast) {
                float e1c = __expf(a0 * dl);
                float p = e1c;
#pragma unroll
                for (int n = 0; n < S; n++) {
                    hh[n] = p * hh[n] + hend[o + n * DI];
                    p *= e1c;
                }
            } else {
#pragma unroll
                for (int n = 0; n < S; n++)
                    hh[n] = __expf(dl * a[n]) * hh[n] + hend[o + n * DI];
            }
        }
    }

    cg::this_grid().sync();

    // ---- phase 3: fixup with register h0, dtcum re-summed (bit-identical) ----
    float h0[S];
    if (ch != 0) {
        size_t o = ((size_t)(b * NCH + ch) * S) * DI + d;
#pragma unroll
        for (int n = 0; n < S; n++) h0[n] = hinit[o + n * DI];
    }
    if (!LAST) {
        float ds2 = 0.f;
        for (int t = t0; t < t1; t++) {
            size_t idx = ((size_t)b * L + t) * DI + d;
            ds2 += dtbuf[idx];
            float y = ysm[t - t0][d];
            if (ch != 0) {
                const float* cv = xdb + ((size_t)b * L + t) * 44 + R + S;  // uniform
                float corr = 0.f;
                if (fast) {
                    float e1c = __expf(a0 * ds2);
                    float p = e1c;
#pragma unroll
                    for (int n = 0; n < S; n++) {
                        corr += cv[n] * p * h0[n];
                        p *= e1c;
                    }
                } else {
#pragma unroll
                    for (int n = 0; n < S; n++)
                        corr += cv[n] * __expf(negA_l[n * DI + d] * ds2) * h0[n];
                }
                y += corr;
            }
            float z = bf2f(z_bf[idx]);
            y_out[idx] = f2bf(y * siluf(z));
        }
    } else {
        if (ch == P / CH) {   // only the cls-token chunk produces output
            float ds2 = 0.f;
            for (int t = t0; t <= P; t++) ds2 += dtbuf[((size_t)b * L + t) * DI + d];
            size_t idx = ((size_t)b * L + P) * DI + d;
            float y = ysm[P - t0][d];
            {
                const float* cv = xdb + ((size_t)b * L + P) * 44 + R + S;
                float corr = 0.f;
                if (fast) {
                    float e1c = __expf(a0 * ds2);
                    float p = e1c;
#pragma unroll
                    for (int n = 0; n < S; n++) {
                        corr += cv[n] * p * h0[n];
                        p *= e1c;
                    }
                } else {
#pragma unroll
                    for (int n = 0; n < S; n++)
                        corr += cv[n] * __expf(negA_l[n * DI + d] * ds2) * h0[n];
                }
                y += corr;
            }
            float z = bf2f(z_bf[idx]);
            y_out[(size_t)b * DI + d] = f2bf(y * siluf(z));   // compact y32 [b][d]
        }
    }
}

// ---------------------------------------------------------------------------
// K5: final rmsnorm of token 400 of (resid+hidden32), then head matmul -> out
// ---------------------------------------------------------------------------
__global__ void k_head(const float* __restrict__ resid, const float* __restrict__ hidden32,
                       const float* __restrict__ norm_f_w, const float* __restrict__ head_w,
                       const float* __restrict__ head_b, float* __restrict__ out) {
    __shared__ float v[E];
    int b = blockIdx.x;
    int lane = threadIdx.x;
    size_t base = ((size_t)b * L + P) * E;
    float loc[3];
    float ss = 0.f;
#pragma unroll
    for (int j = 0; j < 3; j++) {
        int e = lane + j * 64;
        float x = resid[base + e] + hidden32[(size_t)b * E + e];
        loc[j] = x;
        ss += x * x;
    }
#pragma unroll
    for (int off = 32; off > 0; off >>= 1) ss += __shfl_xor(ss, off, 64);
    float scale = rsqrtf(ss * (1.f / (float)E) + 1e-5f);
#pragma unroll
    for (int j = 0; j < 3; j++) {
        int e = lane + j * 64;
        v[e] = loc[j] * scale * norm_f_w[e];
    }
    __syncthreads();
    if (lane < NC) {
        float acc = head_b[lane];
        for (int e = 0; e < E; e++) acc += v[e] * head_w[lane * E + e];
        out[b * NC + lane] = acc;
    }
}

// ---------------------------------------------------------------------------
extern "C" void kernel_launch(void* const* d_in, const int* in_sizes, int n_in,
                              void* d_out, int out_size, void* d_ws, size_t ws_size,
                              hipStream_t stream) {
    const float* imgs      = (const float*)d_in[0];
    const float* patch_w   = (const float*)d_in[1];
    const float* patch_b   = (const float*)d_in[2];
    const float* cls_token = (const float*)d_in[3];
    const float* pos_embed = (const float*)d_in[4];
    const float* cnn_w     = (const float*)d_in[5];
    const float* cnn_b     = (const float*)d_in[6];
    const float* norm_w    = (const float*)d_in[7];
    const float* in_proj_w = (const float*)d_in[8];
    const float* conv_w    = (const float*)d_in[9];
    const float* conv_b    = (const float*)d_in[10];
    const float* x_proj_w  = (const float*)d_in[11];
    const float* dt_proj_w = (const float*)d_in[12];
    const float* dt_proj_b = (const float*)d_in[13];
    const float* A_log     = (const float*)d_in[14];
    const float* Dskip     = (const float*)d_in[15];
    const float* out_proj_w= (const float*)d_in[16];
    const float* norm_f_w  = (const float*)d_in[17];
    const float* head_w    = (const float*)d_in[18];
    const float* head_b    = (const float*)d_in[19];

    float* ws = (float*)d_ws;
    size_t off = 0;
    float* resid  = ws + off; off += (size_t)NTOK * E;
    float* xdb    = ws + off; off += (size_t)NTOK * 44;
    float* dtbuf  = ws + off; off += (size_t)NTOK * DI;             // f32 dt only
    float* hend   = ws + off; off += (size_t)BATCH * NCH * DI * S;  // [b][ch][n][d]
    float* hinit  = ws + off; off += (size_t)BATCH * NCH * DI * S;  // [b][ch][n][d]
    float* dtlast = ws + off; off += (size_t)BATCH * NCH * DI;      // chunk-final dtcum
    float* negA   = ws + off; off += (size_t)DEPTH * DI * S;        // [layer][n][d]
    float* dtw_t  = ws + off; off += (size_t)DEPTH * DI * R;        // [layer][r][d]
    float* hid32  = ws + off; off += (size_t)BATCH * E;             // compact last hidden
    int*   gflag  = (int*)(ws + off); off += (size_t)DEPTH * DI;    // [layer][d]
    unsigned short* xm_bf  = (unsigned short*)(ws + off); off += (size_t)NTOK * DI / 2;
    unsigned short* z_bf   = (unsigned short*)(ws + off); off += (size_t)NTOK * DI / 2;
    unsigned short* bf_buf = (unsigned short*)(ws + off); off += (size_t)NTOK * DI / 2;
    unsigned short* y32_bf = (unsigned short*)(ws + off); off += (size_t)BATCH * DI / 2 + 16;
    unsigned short* w_in  = (unsigned short*)(ws + off); off += (size_t)DEPTH * 2 * DI * E / 2;
    unsigned short* w_x   = (unsigned short*)(ws + off); off += (size_t)DEPTH * 44 * DI / 2 + 16;
    unsigned short* w_out = (unsigned short*)(ws + off); off += (size_t)DEPTH * E * DI / 2;

    // shared bf16 buffer, disjoint live ranges:
    // hn_bf: rmsnorm -> in_proj; xc_bf: conv -> scan; y_bf: scan -> out_proj
    unsigned short* hn_bf = bf_buf;   // [NTOK, E]
    unsigned short* xc_bf = bf_buf;   // [NTOK, DI]
    unsigned short* y_bf  = bf_buf;   // [NTOK, DI]

    {
        int ntot = DEPTH * (2 * DI * E + 44 * DI + E * DI + DI * S + DI * R);
        k_prep<<<(ntot + 255) / 256, 256, 0, stream>>>(in_proj_w, x_proj_w, out_proj_w, A_log,
                                                       dt_proj_w, w_in, w_x, w_out, negA,
                                                       dtw_t);
        k_flag<<<(DEPTH * DI + 255) / 256, 256, 0, stream>>>(negA, gflag);
    }

    k_embed<<<(NTOK * E) / 256, 256, 0, stream>>>(imgs, patch_w, patch_b, cls_token,
                                                  pos_embed, cnn_w, cnn_b, resid);

    for (int i = 0; i < DEPTH; i++) {
        // hn = rmsnorm(resid)*w  (resid already includes all prior hiddens)
        k_rmsnorm<<<NTOK / 4, 256, 0, stream>>>(resid, hn_bf, norm_w + i * E);

        // in_proj: [NTOK,192]bf16 x [768,192]bf16^T -> split: xm bf16 + z bf16
        {
            dim3 g((2 * DI) / 64, (NTOK + 127) / 128);
            k_gemm_bf16<128, 64, 64, 1><<<g, 256, 0, stream>>>(
                hn_bf, w_in + (size_t)i * 2 * DI * E, nullptr, xm_bf, z_bf, NTOK, 2 * DI, E);
        }
        // causal conv4 + silu -> xc_bf
        k_conv<<<(NTOK * DI) / 256, 256, 0, stream>>>(xm_bf, conv_w + (size_t)i * DI * 4,
                                                      conv_b + (size_t)i * DI, xc_bf);
        // x_proj: [NTOK,384]bf16 x [44,384]bf16^T -> xdb f32 [NTOK,44]
        {
            dim3 g(1, NTOK / 32);
            k_gemm_bf16<32, 64, 128, 0><<<g, 256, 0, stream>>>(
                xc_bf, w_x + (size_t)i * 44 * DI, xdb, nullptr, nullptr, NTOK, 44, DI);
        }
        const float* nA = negA + (size_t)i * DI * S;
        const int* fl = gflag + (size_t)i * DI;
        // dt_proj + softplus -> f32 dt (block per token, throughput-parallel)
        k_dtpre<<<NTOK, 384, 0, stream>>>(xdb, dtw_t + (size_t)i * DI * R,
                                          dt_proj_b + (size_t)i * DI, dtbuf);

        // fused cooperative scan (scanA+scanB+fixup): -> y_bf (or y32 last)
        {
            const unsigned short* p_xc = xc_bf;
            const float* p_xdb = xdb;
            const float* p_dt = dtbuf;
            const float* p_nA = nA;
            const int* p_fl = fl;
            const float* p_dsk = Dskip + (size_t)i * DI;
            const unsigned short* p_z = z_bf;
            float* p_hend = hend;
            float* p_dtl = dtlast;
            float* p_hinit = hinit;
            unsigned short* p_y = (i < DEPTH - 1) ? y_bf : y32_bf;
            void* kargs[] = {(void*)&p_xc, (void*)&p_xdb, (void*)&p_dt, (void*)&p_nA,
                             (void*)&p_fl, (void*)&p_dsk, (void*)&p_z, (void*)&p_hend,
                             (void*)&p_dtl, (void*)&p_hinit, (void*)&p_y};
            if (i < DEPTH - 1)
                hipLaunchCooperativeKernel((const void*)k_scan_fused<false>,
                                           dim3(NCH, BATCH), dim3(DI), kargs, 0, stream);
            else
                hipLaunchCooperativeKernel((const void*)k_scan_fused<true>,
                                           dim3(NCH, BATCH), dim3(DI), kargs, 0, stream);
        }

        if (i < DEPTH - 1) {
            // out_proj + residual accumulate: resid += y_bf @ w_out^T
            dim3 go(E / 64, (NTOK + 63) / 64);
            k_gemm_bf16<64, 64, 128, 2><<<go, 256, 0, stream>>>(
                y_bf, w_out + (size_t)i * E * DI, resid, nullptr, nullptr, NTOK, E, DI);
        } else {
            // out_proj on 32 rows only: [32,384] x [192,384]^T -> hid32 [32,192]
            dim3 go(E / 64, 1);
            k_gemm_bf16<32, 64, 128, 0><<<go, 256, 0, stream>>>(
                y32_bf, w_out + (size_t)i * E * DI, hid32, nullptr, nullptr, BATCH, E, DI);
        }
    }

    k_head<<<BATCH, 64, 0, stream>>>(resid, hid32, norm_f_w, head_w, head_b, (float*)d_out);
}

// Round 12
// 755.905 us; speedup vs baseline: 1.6395x; 1.6395x over previous
//
#include <hip/hip_runtime.h>
#include <math.h>

#define E 192
#define DI 384
#define S 16
#define R 12
#define DEPTH 4
#define P 400
#define NC 20
#define BATCH 32
#define L 401
#define NTOK (BATCH * L)   // 12832
#define CH 32
#define NCH 13             // ceil(401/32)

using short8 = __attribute__((ext_vector_type(8))) short;
using float4v = __attribute__((ext_vector_type(4))) float;

__device__ __forceinline__ float siluf(float x) {
    return x / (1.f + __expf(-x));
}
__device__ __forceinline__ float softplusf(float x) {
    return (x > 20.f) ? x : log1pf(__expf(x));
}
// f32 -> bf16 round-to-nearest-even (bit-level; no __hip_bfloat16 dep)
__device__ __forceinline__ unsigned short f2bf(float x) {
    unsigned int u = __float_as_uint(x);
    unsigned int r = 0x7fffu + ((u >> 16) & 1u);
    return (unsigned short)((u + r) >> 16);
}
__device__ __forceinline__ float bf2f(unsigned short v) {
    return __uint_as_float(((unsigned int)v) << 16);
}

// ---------------------------------------------------------------------------
// K0: patch embed + pos + depthwise conv3 + cls token  -> resid[b,l,e]
// ---------------------------------------------------------------------------
__global__ void k_embed(const float* __restrict__ imgs, const float* __restrict__ patch_w,
                        const float* __restrict__ patch_b, const float* __restrict__ cls_token,
                        const float* __restrict__ pos_embed, const float* __restrict__ cnn_w,
                        const float* __restrict__ cnn_b, float* __restrict__ resid) {
    int idx = blockIdx.x * blockDim.x + threadIdx.x;
    if (idx >= NTOK * E) return;
    int e = idx % E;
    int bl = idx / E;
    int l = bl % L;
    int b = bl / L;
    float out;
    if (l == P) {
        out = cls_token[e] + pos_embed[(size_t)P * E + e];
    } else {
        float w0 = patch_w[e * 4 + 0], w1 = patch_w[e * 4 + 1];
        float w2 = patch_w[e * 4 + 2], w3 = patch_w[e * 4 + 3];
        float pb = patch_b[e];
        const float* ib = imgs + (size_t)b * 1600;
        auto xe = [&](int ll) -> float {
            const float* ip = ib + ll * 4;
            return ip[0] * w0 + ip[1] * w1 + ip[2] * w2 + ip[3] * w3 + pb +
                   pos_embed[(size_t)ll * E + e];
        };
        float c0 = cnn_w[e * 3 + 0], c1 = cnn_w[e * 3 + 1], c2 = cnn_w[e * 3 + 2];
        float acc = cnn_b[e] + xe(l) * c1;
        if (l > 0) acc += xe(l - 1) * c0;
        if (l < P - 1) acc += xe(l + 1) * c2;
        out = acc;
    }
    resid[idx] = out;
}

// ---------------------------------------------------------------------------
// K1: hn = rmsnorm(resid)*w -> bf16 (read-only resid; accumulate is in
// out_proj's EPI=2 epilogue).
// ---------------------------------------------------------------------------
__global__ void k_rmsnorm(const float* __restrict__ resid, unsigned short* __restrict__ hn,
                          const float* __restrict__ w) {
    int wave = blockIdx.x * (blockDim.x >> 6) + (threadIdx.x >> 6);
    int lane = threadIdx.x & 63;
    if (wave >= NTOK) return;
    size_t base = (size_t)wave * E;
    float v[3];
    float ss = 0.f;
#pragma unroll
    for (int j = 0; j < 3; j++) {
        int e = lane + j * 64;
        float r = resid[base + e];
        v[j] = r;
        ss += r * r;
    }
#pragma unroll
    for (int off = 32; off > 0; off >>= 1) ss += __shfl_xor(ss, off, 64);
    float scale = rsqrtf(ss * (1.f / (float)E) + 1e-5f);
#pragma unroll
    for (int j = 0; j < 3; j++) {
        int e = lane + j * 64;
        hn[base + e] = f2bf(v[j] * scale * w[e]);
    }
}

// ---------------------------------------------------------------------------
// K_prep: weight bf16 conversions + transposed negA ([layer][n][d]) +
// transposed dt weights ([layer][r][d]) in one kernel.
// ---------------------------------------------------------------------------
__global__ void k_prep(const float* __restrict__ in_proj_w, const float* __restrict__ x_proj_w,
                       const float* __restrict__ out_proj_w, const float* __restrict__ A_log,
                       const float* __restrict__ dt_proj_w,
                       unsigned short* __restrict__ w_in, unsigned short* __restrict__ w_x,
                       unsigned short* __restrict__ w_out, float* __restrict__ negA,
                       float* __restrict__ dtw_t) {
    const int n1 = DEPTH * 2 * DI * E;
    const int n2 = DEPTH * 44 * DI;
    const int n3 = DEPTH * E * DI;
    const int n4 = DEPTH * DI * S;
    const int n5 = DEPTH * DI * R;
    int idx = blockIdx.x * blockDim.x + threadIdx.x;
    if (idx < n1) {
        w_in[idx] = f2bf(in_proj_w[idx]);
    } else if (idx < n1 + n2) {
        int i = idx - n1;
        w_x[i] = f2bf(x_proj_w[i]);
    } else if (idx < n1 + n2 + n3) {
        int i = idx - n1 - n2;
        w_out[i] = f2bf(out_proj_w[i]);
    } else if (idx < n1 + n2 + n3 + n4) {
        int i = idx - n1 - n2 - n3;
        int layer = i / (DI * S);
        int rem = i % (DI * S);
        int n = rem / DI;
        int d = rem % DI;
        negA[i] = -__expf(A_log[(size_t)layer * DI * S + d * S + n]);
    } else if (idx < n1 + n2 + n3 + n4 + n5) {
        int i = idx - n1 - n2 - n3 - n4;
        int layer = i / (DI * R);
        int rem = i % (DI * R);
        int r = rem / DI;
        int d = rem % DI;
        dtw_t[i] = dt_proj_w[(size_t)layer * DI * R + d * R + r];
    }
}

// K_flag: per (layer,d): is a_n == (n+1)*a_0 for all n? -> pow-chain eligible
__global__ void k_flag(const float* __restrict__ negA, int* __restrict__ flag) {
    int idx = blockIdx.x * blockDim.x + threadIdx.x;
    if (idx >= DEPTH * DI) return;
    int layer = idx / DI;
    int d = idx % DI;
    const float* base = negA + (size_t)layer * DI * S;
    float a0 = base[d];
    bool ok = true;
#pragma unroll
    for (int n = 1; n < S; n++) {
        float an = base[n * DI + d];
        ok = ok && (fabsf(an - (float)(n + 1) * a0) <= 1e-5f * fabsf(an));
    }
    flag[idx] = ok ? 1 : 0;
}

// ---------------------------------------------------------------------------
// K2: bf16 MFMA GEMM  C = A[M,K](bf16) * W[N,K](bf16)^T
// block 256 (4 waves, 2x2 over (M,N)), tile BM x BN, K-tile BK.
// BK is a free parameter: accumulation order is monotonic in K for any BK ->
// results BIT-IDENTICAL across BK (verified R7: absmax unchanged).
// EPI=0: C[M,N] f32.
// EPI=1 (in_proj split): n<DI -> XMbf16[m*DI+n] (xm), n>=DI -> Zbf16 (z gate).
// EPI=2: C[M,N] += acc  (out_proj fused residual accumulate)
// ---------------------------------------------------------------------------
template <int BM, int BN, int BK, int EPI>
__global__ __launch_bounds__(256) void k_gemm_bf16(const unsigned short* __restrict__ A,
                                                   const unsigned short* __restrict__ W,
                                                   float* __restrict__ C,
                                                   unsigned short* __restrict__ XM,
                                                   unsigned short* __restrict__ Z,
                                                   int M, int N, int K) {
    constexpr int PADK = BK + 8;
    constexpr int MT = BM / 32, NT = BN / 32;
    __shared__ unsigned short As[BM][PADK];
    __shared__ unsigned short Bs[BN][PADK];
    int tid = threadIdx.x;
    int m0 = blockIdx.y * BM, n0 = blockIdx.x * BN;
    int wave = tid >> 6, lane = tid & 63;
    int row16 = lane & 15, quad = lane >> 4;
    int wm0 = (wave >> 1) * (BM / 2), wn0 = (wave & 1) * (BN / 2);

    float4v acc[MT][NT];
#pragma unroll
    for (int i = 0; i < MT; i++)
#pragma unroll
        for (int j = 0; j < NT; j++) acc[i][j] = (float4v){0.f, 0.f, 0.f, 0.f};

    for (int k0 = 0; k0 < K; k0 += BK) {
#pragma unroll
        for (int idx = tid * 8; idx < BM * BK; idx += 256 * 8) {
            int row = idx / BK, col = idx % BK;
            int gm = m0 + row;
            short8 v;
            if (gm < M)
                v = *(const short8*)&A[(size_t)gm * K + k0 + col];
            else
                v = (short8)0;
            *(short8*)&As[row][col] = v;
        }
#pragma unroll
        for (int idx = tid * 8; idx < BN * BK; idx += 256 * 8) {
            int row = idx / BK, col = idx % BK;
            int gn = n0 + row;
            short8 v;
            if (gn < N)
                v = *(const short8*)&W[(size_t)gn * K + k0 + col];
            else
                v = (short8)0;
            *(short8*)&Bs[row][col] = v;
        }
        __syncthreads();
#pragma unroll
        for (int kk = 0; kk < BK; kk += 32) {
            int koff = kk + quad * 8;
            short8 af[MT], bfr[NT];
#pragma unroll
            for (int i = 0; i < MT; i++)
                af[i] = *(const short8*)&As[wm0 + i * 16 + row16][koff];
#pragma unroll
            for (int j = 0; j < NT; j++)
                bfr[j] = *(const short8*)&Bs[wn0 + j * 16 + row16][koff];
#pragma unroll
            for (int i = 0; i < MT; i++)
#pragma unroll
                for (int j = 0; j < NT; j++)
                    acc[i][j] = __builtin_amdgcn_mfma_f32_16x16x32_bf16(af[i], bfr[j],
                                                                        acc[i][j], 0, 0, 0);
        }
        __syncthreads();
    }
#pragma unroll
    for (int i = 0; i < MT; i++) {
#pragma unroll
        for (int j = 0; j < NT; j++) {
#pragma unroll
            for (int r = 0; r < 4; r++) {
                int m = m0 + wm0 + i * 16 + quad * 4 + r;
                int n = n0 + wn0 + j * 16 + row16;
                if (m >= M || n >= N) continue;
                float v = acc[i][j][r];
                if (EPI == 0) {
                    C[(size_t)m * N + n] = v;
                } else if (EPI == 1) {
                    if (n < DI)
                        XM[(size_t)m * DI + n] = f2bf(v);
                    else
                        Z[(size_t)m * DI + (n - DI)] = f2bf(v);
                } else {
                    C[(size_t)m * N + n] += v;  // residual accumulate
                }
            }
        }
    }
}

// ---------------------------------------------------------------------------
// K3: causal depthwise conv4 + SiLU over xm(bf16) -> xc_bf (bf16)
// (kept as a streaming kernel ON PURPOSE; every fusion/replacement attempt
//  of the conv/x_proj/dt slot regressed: R2 +36, R3 +85, R5 +165, R6 +130.)
// ---------------------------------------------------------------------------
__global__ void k_conv(const unsigned short* __restrict__ xm_bf, const float* __restrict__ cw,
                       const float* __restrict__ cb, unsigned short* __restrict__ xc_bf) {
    int idx = blockIdx.x * blockDim.x + threadIdx.x;
    if (idx >= NTOK * DI) return;
    int d = idx % DI;
    int bl = idx / DI;
    int l = bl % L;
    int b = bl / L;
    const unsigned short* base = xm_bf + (size_t)b * L * DI + d;
    float acc = cb[d];
#pragma unroll
    for (int k = 0; k < 4; k++) {
        int ll = l - 3 + k;
        if (ll >= 0) acc += bf2f(base[(size_t)ll * DI]) * cw[d * 4 + k];
    }
    xc_bf[idx] = f2bf(siluf(acc));
}

// ---------------------------------------------------------------------------
// K_dtpre: one block per token. dt = softplus(xdb_row . dtw_t + dtb) -> f32.
// ---------------------------------------------------------------------------
__global__ __launch_bounds__(384) void k_dtpre(
        const float* __restrict__ xdb, const float* __restrict__ dtw_t,
        const float* __restrict__ dtb, float* __restrict__ dtbuf) {
    int tok = blockIdx.x;
    int d = threadIdx.x;
    const float* xr = xdb + (size_t)tok * 44;
    float acc = dtb[d];
#pragma unroll
    for (int r = 0; r < R; r++) acc += xr[r] * dtw_t[r * DI + d];
    dtbuf[(size_t)tok * DI + d] = softplusf(acc);
}

// ---------------------------------------------------------------------------
// K4a: chunk-local scan. R12: depth-3 software pipeline for the dtbuf/xc
// loads (was depth-1): loads for t+3 issue ~3 bodies (~500-700 cyc) before
// use, covering L2/HBM latency at this kernel's low 2.4 waves/SIMD TLP.
// Compute order per step is UNCHANGED (e1 for t+1 still computed during t's
// body; same ops, same values) -> bit-identical results.
// hend in [b][ch][n][d] layout. Writes packed ydt {y_local, dtcum}.
// LAST=true: only write ydt at t==P and chunk-last tokens.
// grid (NCH, BATCH) x 384 threads (d per thread). min chunk len 17 > 3 so
// the 3-deep prologue needs no bounds guards.
// ---------------------------------------------------------------------------
template <bool LAST>
__global__ __launch_bounds__(384) void k_scanA(
        const unsigned short* __restrict__ xc_bf, const float* __restrict__ xdb,
        const float* __restrict__ dtbuf, const float* __restrict__ negA_l,
        const int* __restrict__ flag_l, const float* __restrict__ Dskip,
        float2* __restrict__ ydt, float* __restrict__ hend) {
    int d = threadIdx.x;
    int ch = blockIdx.x;
    int b = blockIdx.y;
    int t0 = ch * CH;
    int t1 = min(t0 + CH, L);
    bool fast = __all(flag_l[d] != 0);
    float a0 = negA_l[d];
    float a[S];
    if (!fast) {
#pragma unroll
        for (int n = 0; n < S; n++) a[n] = negA_l[n * DI + d];
    }
    float dsk = Dskip[d];
    float h[S] = {};
    float dts = 0.f;
    size_t tok0 = (size_t)b * L + t0;
    // depth-3 pipeline registers: A = t, B = t+1, C = t+2
    float dtA = dtbuf[tok0 * DI + d];
    float uA = bf2f(xc_bf[tok0 * DI + d]);
    float dtB = dtbuf[(tok0 + 1) * DI + d];
    float uB = bf2f(xc_bf[(tok0 + 1) * DI + d]);
    float dtC = dtbuf[(tok0 + 2) * DI + d];
    float uC = bf2f(xc_bf[(tok0 + 2) * DI + d]);
    float e1A = __expf(a0 * dtA);
    for (int t = t0; t < t1; t++) {
        size_t tok = (size_t)b * L + t;
        float dtv = dtA, e1v = e1A, uu = uA;
        // issue load for t+3 (3 bodies ahead); compute e1 for t+1 (as before)
        float dtD = 0.f, uD = 0.f;
        if (t + 3 < t1) {
            dtD = dtbuf[(tok + 3) * DI + d];
            uD = bf2f(xc_bf[(tok + 3) * DI + d]);
        }
        if (t + 1 < t1) e1A = __expf(a0 * dtB);
        const float* row = xdb + tok * 44;   // block-uniform -> s_loads
        dts += dtv;
        float dtu = dtv * uu;
        float y = uu * dsk;
        if (fast) {
            float p = e1v;
#pragma unroll
            for (int n = 0; n < S; n++) {
                h[n] = p * h[n] + dtu * row[R + n];
                y += h[n] * row[R + S + n];
                p *= e1v;
            }
        } else {
#pragma unroll
            for (int n = 0; n < S; n++) {
                float dA = __expf(dtv * a[n]);
                h[n] = dA * h[n] + dtu * row[R + n];
                y += h[n] * row[R + S + n];
            }
        }
        if (!LAST || t == P || t == t1 - 1) ydt[tok * DI + d] = make_float2(y, dts);
        dtA = dtB; uA = uB;
        dtB = dtC; uB = uC;
        dtC = dtD; uC = uD;
    }
    float* he = hend + ((size_t)(b * NCH + ch) * S) * DI + d;
#pragma unroll
    for (int n = 0; n < S; n++) he[n * DI] = h[n];
}

// ---------------------------------------------------------------------------
// K4b: combine chunk prefixes serially (NCH chunks) -> h_init per chunk.
// ---------------------------------------------------------------------------
__global__ void k_scanB(const float* __restrict__ hend, const float2* __restrict__ ydt,
                        const float* __restrict__ negA_l, const int* __restrict__ flag_l,
                        float* __restrict__ hinit) {
    int idx = blockIdx.x * blockDim.x + threadIdx.x;
    if (idx >= BATCH * DI) return;
    int d = idx % DI;
    int b = idx / DI;
    bool fast = __all(flag_l[d] != 0);
    float a[S];
#pragma unroll
    for (int n = 0; n < S; n++) a[n] = negA_l[n * DI + d];
    float h[S] = {};
    for (int ch = 0; ch < NCH; ch++) {
        size_t o = ((size_t)(b * NCH + ch) * S) * DI + d;
#pragma unroll
        for (int n = 0; n < S; n++) hinit[o + n * DI] = h[n];
        int tlast = min(ch * CH + CH, L) - 1;
        float dts = ydt[((size_t)b * L + tlast) * DI + d].y;
        if (fast) {
            float e1c = __expf(a[0] * dts);
            float p = e1c;
#pragma unroll
            for (int n = 0; n < S; n++) {
                h[n] = p * h[n] + hend[o + n * DI];
                p *= e1c;
            }
        } else {
#pragma unroll
            for (int n = 0; n < S; n++) h[n] = __expf(dts * a[n]) * h[n] + hend[o + n * DI];
        }
    }
}

// ---------------------------------------------------------------------------
// K4c: fixup, one block per token: y = (y_local + sum_n c_n exp(a_n dtcum) h0_n)
//      * silu(z) -> bf16. cv row block-uniform; h0 coalesced; z from bf16.
// ---------------------------------------------------------------------------
__global__ __launch_bounds__(384) void k_fixup(
        const unsigned short* __restrict__ z_bf, const float* __restrict__ xdb,
        const float* __restrict__ negA_l, const int* __restrict__ flag_l,
        const float* __restrict__ hinit, const float2* __restrict__ ydt,
        unsigned short* __restrict__ y_bf) {
    int tok = blockIdx.x;
    int d = threadIdx.x;
    int l = tok % L;
    int b = tok / L;
    int ch = l / CH;
    size_t idx = (size_t)tok * DI + d;
    float2 yd = ydt[idx];
    float y = yd.x;
    if (ch != 0) {
        bool fast = __all(flag_l[d] != 0);
        const float* h0 = hinit + ((size_t)(b * NCH + ch) * S) * DI + d;
        const float* cv = xdb + (size_t)tok * 44 + R + S;  // block-uniform
        float dts = yd.y;
        float corr = 0.f;
        if (fast) {
            float e1c = __expf(negA_l[d] * dts);
            float p = e1c;
#pragma unroll
            for (int n = 0; n < S; n++) {
                corr += cv[n] * p * h0[n * DI];
                p *= e1c;
            }
        } else {
#pragma unroll
            for (int n = 0; n < S; n++)
                corr += cv[n] * __expf(negA_l[n * DI + d] * dts) * h0[n * DI];
        }
        y += corr;
    }
    float z = bf2f(z_bf[idx]);
    y_bf[idx] = f2bf(y * siluf(z));
}

// ---------------------------------------------------------------------------
// K4c-last: fixup only for the 32 cls tokens (b*L+P) -> compact y32 [b][d]
// ---------------------------------------------------------------------------
__global__ __launch_bounds__(384) void k_fixup_last(
        const unsigned short* __restrict__ z_bf, const float* __restrict__ xdb,
        const float* __restrict__ negA_l, const int* __restrict__ flag_l,
        const float* __restrict__ hinit, const float2* __restrict__ ydt,
        unsigned short* __restrict__ y32) {
    int b = blockIdx.x;
    int d = threadIdx.x;
    int tok = b * L + P;
    int ch = P / CH;   // last chunk
    size_t idx = (size_t)tok * DI + d;
    float2 yd = ydt[idx];
    float y = yd.x;
    {
        bool fast = __all(flag_l[d] != 0);
        const float* h0 = hinit + ((size_t)(b * NCH + ch) * S) * DI + d;
        const float* cv = xdb + (size_t)tok * 44 + R + S;
        float dts = yd.y;
        float corr = 0.f;
        if (fast) {
            float e1c = __expf(negA_l[d] * dts);
            float p = e1c;
#pragma unroll
            for (int n = 0; n < S; n++) {
                corr += cv[n] * p * h0[n * DI];
                p *= e1c;
            }
        } else {
#pragma unroll
            for (int n = 0; n < S; n++)
                corr += cv[n] * __expf(negA_l[n * DI + d] * dts) * h0[n * DI];
        }
        y += corr;
    }
    float z = bf2f(z_bf[idx]);
    y32[(size_t)b * DI + d] = f2bf(y * siluf(z));
}

// ---------------------------------------------------------------------------
// K5: final rmsnorm of token 400 of (resid+hidden32), then head matmul -> out
// ---------------------------------------------------------------------------
__global__ void k_head(const float* __restrict__ resid, const float* __restrict__ hidden32,
                       const float* __restrict__ norm_f_w, const float* __restrict__ head_w,
                       const float* __restrict__ head_b, float* __restrict__ out) {
    __shared__ float v[E];
    int b = blockIdx.x;
    int lane = threadIdx.x;
    size_t base = ((size_t)b * L + P) * E;
    float loc[3];
    float ss = 0.f;
#pragma unroll
    for (int j = 0; j < 3; j++) {
        int e = lane + j * 64;
        float x = resid[base + e] + hidden32[(size_t)b * E + e];
        loc[j] = x;
        ss += x * x;
    }
#pragma unroll
    for (int off = 32; off > 0; off >>= 1) ss += __shfl_xor(ss, off, 64);
    float scale = rsqrtf(ss * (1.f / (float)E) + 1e-5f);
#pragma unroll
    for (int j = 0; j < 3; j++) {
        int e = lane + j * 64;
        v[e] = loc[j] * scale * norm_f_w[e];
    }
    __syncthreads();
    if (lane < NC) {
        float acc = head_b[lane];
        for (int e = 0; e < E; e++) acc += v[e] * head_w[lane * E + e];
        out[b * NC + lane] = acc;
    }
}

// ---------------------------------------------------------------------------
extern "C" void kernel_launch(void* const* d_in, const int* in_sizes, int n_in,
                              void* d_out, int out_size, void* d_ws, size_t ws_size,
                              hipStream_t stream) {
    const float* imgs      = (const float*)d_in[0];
    const float* patch_w   = (const float*)d_in[1];
    const float* patch_b   = (const float*)d_in[2];
    const float* cls_token = (const float*)d_in[3];
    const float* pos_embed = (const float*)d_in[4];
    const float* cnn_w     = (const float*)d_in[5];
    const float* cnn_b     = (const float*)d_in[6];
    const float* norm_w    = (const float*)d_in[7];
    const float* in_proj_w = (const float*)d_in[8];
    const float* conv_w    = (const float*)d_in[9];
    const float* conv_b    = (const float*)d_in[10];
    const float* x_proj_w  = (const float*)d_in[11];
    const float* dt_proj_w = (const float*)d_in[12];
    const float* dt_proj_b = (const float*)d_in[13];
    const float* A_log     = (const float*)d_in[14];
    const float* Dskip     = (const float*)d_in[15];
    const float* out_proj_w= (const float*)d_in[16];
    const float* norm_f_w  = (const float*)d_in[17];
    const float* head_w    = (const float*)d_in[18];
    const float* head_b    = (const float*)d_in[19];

    float* ws = (float*)d_ws;
    size_t off = 0;
    float* resid  = ws + off; off += (size_t)NTOK * E;
    float* xdb    = ws + off; off += (size_t)NTOK * 44;
    float* dtbuf  = ws + off; off += (size_t)NTOK * DI;             // f32 dt only
    float* ydt    = ws + off; off += (size_t)NTOK * DI * 2;  // packed {y_local,dtcum}
    float* hend   = ws + off; off += (size_t)BATCH * NCH * DI * S;  // [b][ch][n][d]
    float* hinit  = ws + off; off += (size_t)BATCH * NCH * DI * S;  // [b][ch][n][d]
    float* negA   = ws + off; off += (size_t)DEPTH * DI * S;        // [layer][n][d]
    float* dtw_t  = ws + off; off += (size_t)DEPTH * DI * R;        // [layer][r][d]
    float* hid32  = ws + off; off += (size_t)BATCH * E;             // compact last hidden
    int*   gflag  = (int*)(ws + off); off += (size_t)DEPTH * DI;    // [layer][d]
    unsigned short* xm_bf  = (unsigned short*)(ws + off); off += (size_t)NTOK * DI / 2;
    unsigned short* z_bf   = (unsigned short*)(ws + off); off += (size_t)NTOK * DI / 2;
    unsigned short* bf_buf = (unsigned short*)(ws + off); off += (size_t)NTOK * DI / 2;
    unsigned short* y32_bf = (unsigned short*)(ws + off); off += (size_t)BATCH * DI / 2 + 16;
    unsigned short* w_in  = (unsigned short*)(ws + off); off += (size_t)DEPTH * 2 * DI * E / 2;
    unsigned short* w_x   = (unsigned short*)(ws + off); off += (size_t)DEPTH * 44 * DI / 2 + 16;
    unsigned short* w_out = (unsigned short*)(ws + off); off += (size_t)DEPTH * E * DI / 2;

    // shared bf16 buffer, disjoint live ranges:
    // hn_bf: rmsnorm -> in_proj; xc_bf: conv -> scanA; y_bf: fixup -> out_proj
    unsigned short* hn_bf = bf_buf;   // [NTOK, E]
    unsigned short* xc_bf = bf_buf;   // [NTOK, DI]
    unsigned short* y_bf  = bf_buf;   // [NTOK, DI]

    {
        int ntot = DEPTH * (2 * DI * E + 44 * DI + E * DI + DI * S + DI * R);
        k_prep<<<(ntot + 255) / 256, 256, 0, stream>>>(in_proj_w, x_proj_w, out_proj_w, A_log,
                                                       dt_proj_w, w_in, w_x, w_out, negA,
                                                       dtw_t);
        k_flag<<<(DEPTH * DI + 255) / 256, 256, 0, stream>>>(negA, gflag);
    }

    k_embed<<<(NTOK * E) / 256, 256, 0, stream>>>(imgs, patch_w, patch_b, cls_token,
                                                  pos_embed, cnn_w, cnn_b, resid);

    for (int i = 0; i < DEPTH; i++) {
        // hn = rmsnorm(resid)*w  (resid already includes all prior hiddens)
        k_rmsnorm<<<NTOK / 4, 256, 0, stream>>>(resid, hn_bf, norm_w + i * E);

        // in_proj: [NTOK,192]bf16 x [768,192]bf16^T -> split: xm bf16 + z bf16
        {
            dim3 g((2 * DI) / 64, (NTOK + 127) / 128);
            k_gemm_bf16<128, 64, 64, 1><<<g, 256, 0, stream>>>(
                hn_bf, w_in + (size_t)i * 2 * DI * E, nullptr, xm_bf, z_bf, NTOK, 2 * DI, E);
        }
        // causal conv4 + silu -> xc_bf
        k_conv<<<(NTOK * DI) / 256, 256, 0, stream>>>(xm_bf, conv_w + (size_t)i * DI * 4,
                                                      conv_b + (size_t)i * DI, xc_bf);
        // x_proj: [NTOK,384]bf16 x [44,384]bf16^T -> xdb f32 [NTOK,44]
        {
            dim3 g(1, NTOK / 32);
            k_gemm_bf16<32, 64, 128, 0><<<g, 256, 0, stream>>>(
                xc_bf, w_x + (size_t)i * 44 * DI, xdb, nullptr, nullptr, NTOK, 44, DI);
        }
        const float* nA = negA + (size_t)i * DI * S;
        const int* fl = gflag + (size_t)i * DI;
        // dt_proj + softplus -> f32 dt (block per token, throughput-parallel)
        k_dtpre<<<NTOK, 384, 0, stream>>>(xdb, dtw_t + (size_t)i * DI * R,
                                          dt_proj_b + (size_t)i * DI, dtbuf);
        // chunked scan: local scan -> chunk combine -> parallel fixup
        dim3 g(NCH, BATCH);
        if (i < DEPTH - 1) {
            k_scanA<false><<<g, DI, 0, stream>>>(xc_bf, xdb, dtbuf, nA, fl,
                                                 Dskip + (size_t)i * DI, (float2*)ydt, hend);
            k_scanB<<<(BATCH * DI + 255) / 256, 256, 0, stream>>>(hend, (const float2*)ydt,
                                                                  nA, fl, hinit);
            k_fixup<<<NTOK, 384, 0, stream>>>(z_bf, xdb, nA, fl, hinit,
                                              (const float2*)ydt, y_bf);
            // out_proj + residual accumulate: resid += y_bf @ w_out^T
            dim3 go(E / 64, (NTOK + 63) / 64);
            k_gemm_bf16<64, 64, 128, 2><<<go, 256, 0, stream>>>(
                y_bf, w_out + (size_t)i * E * DI, resid, nullptr, nullptr, NTOK, E, DI);
        } else {
            // last layer: only the cls token (P) of each batch feeds the head
            k_scanA<true><<<g, DI, 0, stream>>>(xc_bf, xdb, dtbuf, nA, fl,
                                                Dskip + (size_t)i * DI, (float2*)ydt, hend);
            k_scanB<<<(BATCH * DI + 255) / 256, 256, 0, stream>>>(hend, (const float2*)ydt,
                                                                  nA, fl, hinit);
            k_fixup_last<<<BATCH, 384, 0, stream>>>(z_bf, xdb, nA, fl, hinit,
                                                    (const float2*)ydt, y32_bf);
            // out_proj on 32 rows only: [32,384] x [192,384]^T -> hid32 [32,192]
            dim3 go(E / 64, 1);
            k_gemm_bf16<32, 64, 128, 0><<<go, 256, 0, stream>>>(
                y32_bf, w_out + (size_t)i * E * DI, hid32, nullptr, nullptr, BATCH, E, DI);
        }
    }

    k_head<<<BATCH, 64, 0, stream>>>(resid, hid32, norm_f_w, head_w, head_b, (float*)d_out);
}

// Round 14
// 729.476 us; speedup vs baseline: 1.6989x; 1.0362x over previous
//
#include <hip/hip_runtime.h>
#include <math.h>

#define E 192
#define DI 384
#define S 16
#define R 12
#define DEPTH 4
#define P 400
#define NC 20
#define BATCH 32
#define L 401
#define NTOK (BATCH * L)   // 12832
#define CH 32
#define NCH 13             // ceil(401/32)

using short8 = __attribute__((ext_vector_type(8))) short;
using float4v = __attribute__((ext_vector_type(4))) float;

__device__ __forceinline__ float siluf(float x) {
    return x / (1.f + __expf(-x));
}
__device__ __forceinline__ float softplusf(float x) {
    return (x > 20.f) ? x : log1pf(__expf(x));
}
// f32 -> bf16 round-to-nearest-even (bit-level; no __hip_bfloat16 dep)
__device__ __forceinline__ unsigned short f2bf(float x) {
    unsigned int u = __float_as_uint(x);
    unsigned int r = 0x7fffu + ((u >> 16) & 1u);
    return (unsigned short)((u + r) >> 16);
}
__device__ __forceinline__ float bf2f(unsigned short v) {
    return __uint_as_float(((unsigned int)v) << 16);
}

// ---------------------------------------------------------------------------
// K0: patch embed + pos + depthwise conv3 + cls token  -> resid[b,l,e]
// ---------------------------------------------------------------------------
__global__ void k_embed(const float* __restrict__ imgs, const float* __restrict__ patch_w,
                        const float* __restrict__ patch_b, const float* __restrict__ cls_token,
                        const float* __restrict__ pos_embed, const float* __restrict__ cnn_w,
                        const float* __restrict__ cnn_b, float* __restrict__ resid) {
    int idx = blockIdx.x * blockDim.x + threadIdx.x;
    if (idx >= NTOK * E) return;
    int e = idx % E;
    int bl = idx / E;
    int l = bl % L;
    int b = bl / L;
    float out;
    if (l == P) {
        out = cls_token[e] + pos_embed[(size_t)P * E + e];
    } else {
        float w0 = patch_w[e * 4 + 0], w1 = patch_w[e * 4 + 1];
        float w2 = patch_w[e * 4 + 2], w3 = patch_w[e * 4 + 3];
        float pb = patch_b[e];
        const float* ib = imgs + (size_t)b * 1600;
        auto xe = [&](int ll) -> float {
            const float* ip = ib + ll * 4;
            return ip[0] * w0 + ip[1] * w1 + ip[2] * w2 + ip[3] * w3 + pb +
                   pos_embed[(size_t)ll * E + e];
        };
        float c0 = cnn_w[e * 3 + 0], c1 = cnn_w[e * 3 + 1], c2 = cnn_w[e * 3 + 2];
        float acc = cnn_b[e] + xe(l) * c1;
        if (l > 0) acc += xe(l - 1) * c0;
        if (l < P - 1) acc += xe(l + 1) * c2;
        out = acc;
    }
    resid[idx] = out;
}

// ---------------------------------------------------------------------------
// K1: hn = rmsnorm(resid)*w -> bf16 (read-only resid; accumulate is in
// out_proj's EPI=2 epilogue).
// ---------------------------------------------------------------------------
__global__ void k_rmsnorm(const float* __restrict__ resid, unsigned short* __restrict__ hn,
                          const float* __restrict__ w) {
    int wave = blockIdx.x * (blockDim.x >> 6) + (threadIdx.x >> 6);
    int lane = threadIdx.x & 63;
    if (wave >= NTOK) return;
    size_t base = (size_t)wave * E;
    float v[3];
    float ss = 0.f;
#pragma unroll
    for (int j = 0; j < 3; j++) {
        int e = lane + j * 64;
        float r = resid[base + e];
        v[j] = r;
        ss += r * r;
    }
#pragma unroll
    for (int off = 32; off > 0; off >>= 1) ss += __shfl_xor(ss, off, 64);
    float scale = rsqrtf(ss * (1.f / (float)E) + 1e-5f);
#pragma unroll
    for (int j = 0; j < 3; j++) {
        int e = lane + j * 64;
        hn[base + e] = f2bf(v[j] * scale * w[e]);
    }
}

// ---------------------------------------------------------------------------
// K_prep: weight bf16 conversions + transposed negA ([layer][n][d]) +
// transposed dt weights ([layer][r][d]) in one kernel.
// ---------------------------------------------------------------------------
__global__ void k_prep(const float* __restrict__ in_proj_w, const float* __restrict__ x_proj_w,
                       const float* __restrict__ out_proj_w, const float* __restrict__ A_log,
                       const float* __restrict__ dt_proj_w,
                       unsigned short* __restrict__ w_in, unsigned short* __restrict__ w_x,
                       unsigned short* __restrict__ w_out, float* __restrict__ negA,
                       float* __restrict__ dtw_t) {
    const int n1 = DEPTH * 2 * DI * E;
    const int n2 = DEPTH * 44 * DI;
    const int n3 = DEPTH * E * DI;
    const int n4 = DEPTH * DI * S;
    const int n5 = DEPTH * DI * R;
    int idx = blockIdx.x * blockDim.x + threadIdx.x;
    if (idx < n1) {
        w_in[idx] = f2bf(in_proj_w[idx]);
    } else if (idx < n1 + n2) {
        int i = idx - n1;
        w_x[i] = f2bf(x_proj_w[i]);
    } else if (idx < n1 + n2 + n3) {
        int i = idx - n1 - n2;
        w_out[i] = f2bf(out_proj_w[i]);
    } else if (idx < n1 + n2 + n3 + n4) {
        int i = idx - n1 - n2 - n3;
        int layer = i / (DI * S);
        int rem = i % (DI * S);
        int n = rem / DI;
        int d = rem % DI;
        negA[i] = -__expf(A_log[(size_t)layer * DI * S + d * S + n]);
    } else if (idx < n1 + n2 + n3 + n4 + n5) {
        int i = idx - n1 - n2 - n3 - n4;
        int layer = i / (DI * R);
        int rem = i % (DI * R);
        int r = rem / DI;
        int d = rem % DI;
        dtw_t[i] = dt_proj_w[(size_t)layer * DI * R + d * R + r];
    }
}

// K_flag: per (layer,d): is a_n == (n+1)*a_0 for all n? -> pow-chain eligible
__global__ void k_flag(const float* __restrict__ negA, int* __restrict__ flag) {
    int idx = blockIdx.x * blockDim.x + threadIdx.x;
    if (idx >= DEPTH * DI) return;
    int layer = idx / DI;
    int d = idx % DI;
    const float* base = negA + (size_t)layer * DI * S;
    float a0 = base[d];
    bool ok = true;
#pragma unroll
    for (int n = 1; n < S; n++) {
        float an = base[n * DI + d];
        ok = ok && (fabsf(an - (float)(n + 1) * a0) <= 1e-5f * fabsf(an));
    }
    flag[idx] = ok ? 1 : 0;
}

// ---------------------------------------------------------------------------
// K2: bf16 MFMA GEMM  C = A[M,K](bf16) * W[N,K](bf16)^T
// block 256 (4 waves, 2x2 over (M,N)), tile BM x BN, K-tile BK.
// BK is a free parameter: MFMA K-slice accumulation order is monotonic in K
// for any BK -> results are BIT-IDENTICAL across BK choices; larger BK just
// means fewer barrier pairs. x_proj/out_proj (K=384) use BK=128 -> 3 iters;
// in_proj stays BK=64 (grid 4.7 blocks/CU; larger LDS would cut capacity).
// EPI=0: C[M,N] f32.
// EPI=1 (in_proj split): n<DI -> XMbf16[m*DI+n] (xm), n>=DI -> Zbf16 (z gate).
// EPI=2: C[M,N] += acc  (out_proj fused residual accumulate)
// ---------------------------------------------------------------------------
template <int BM, int BN, int BK, int EPI>
__global__ __launch_bounds__(256) void k_gemm_bf16(const unsigned short* __restrict__ A,
                                                   const unsigned short* __restrict__ W,
                                                   float* __restrict__ C,
                                                   unsigned short* __restrict__ XM,
                                                   unsigned short* __restrict__ Z,
                                                   int M, int N, int K) {
    constexpr int PADK = BK + 8;
    constexpr int MT = BM / 32, NT = BN / 32;
    __shared__ unsigned short As[BM][PADK];
    __shared__ unsigned short Bs[BN][PADK];
    int tid = threadIdx.x;
    int m0 = blockIdx.y * BM, n0 = blockIdx.x * BN;
    int wave = tid >> 6, lane = tid & 63;
    int row16 = lane & 15, quad = lane >> 4;
    int wm0 = (wave >> 1) * (BM / 2), wn0 = (wave & 1) * (BN / 2);

    float4v acc[MT][NT];
#pragma unroll
    for (int i = 0; i < MT; i++)
#pragma unroll
        for (int j = 0; j < NT; j++) acc[i][j] = (float4v){0.f, 0.f, 0.f, 0.f};

    for (int k0 = 0; k0 < K; k0 += BK) {
#pragma unroll
        for (int idx = tid * 8; idx < BM * BK; idx += 256 * 8) {
            int row = idx / BK, col = idx % BK;
            int gm = m0 + row;
            short8 v;
            if (gm < M)
                v = *(const short8*)&A[(size_t)gm * K + k0 + col];
            else
                v = (short8)0;
            *(short8*)&As[row][col] = v;
        }
#pragma unroll
        for (int idx = tid * 8; idx < BN * BK; idx += 256 * 8) {
            int row = idx / BK, col = idx % BK;
            int gn = n0 + row;
            short8 v;
            if (gn < N)
                v = *(const short8*)&W[(size_t)gn * K + k0 + col];
            else
                v = (short8)0;
            *(short8*)&Bs[row][col] = v;
        }
        __syncthreads();
#pragma unroll
        for (int kk = 0; kk < BK; kk += 32) {
            int koff = kk + quad * 8;
            short8 af[MT], bfr[NT];
#pragma unroll
            for (int i = 0; i < MT; i++)
                af[i] = *(const short8*)&As[wm0 + i * 16 + row16][koff];
#pragma unroll
            for (int j = 0; j < NT; j++)
                bfr[j] = *(const short8*)&Bs[wn0 + j * 16 + row16][koff];
#pragma unroll
            for (int i = 0; i < MT; i++)
#pragma unroll
                for (int j = 0; j < NT; j++)
                    acc[i][j] = __builtin_amdgcn_mfma_f32_16x16x32_bf16(af[i], bfr[j],
                                                                        acc[i][j], 0, 0, 0);
        }
        __syncthreads();
    }
#pragma unroll
    for (int i = 0; i < MT; i++) {
#pragma unroll
        for (int j = 0; j < NT; j++) {
#pragma unroll
            for (int r = 0; r < 4; r++) {
                int m = m0 + wm0 + i * 16 + quad * 4 + r;
                int n = n0 + wn0 + j * 16 + row16;
                if (m >= M || n >= N) continue;
                float v = acc[i][j][r];
                if (EPI == 0) {
                    C[(size_t)m * N + n] = v;
                } else if (EPI == 1) {
                    if (n < DI)
                        XM[(size_t)m * DI + n] = f2bf(v);
                    else
                        Z[(size_t)m * DI + (n - DI)] = f2bf(v);
                } else {
                    C[(size_t)m * N + n] += v;  // residual accumulate
                }
            }
        }
    }
}

// ---------------------------------------------------------------------------
// K3: causal depthwise conv4 + SiLU over xm(bf16) -> xc_bf (bf16)
// (kept as a streaming kernel ON PURPOSE; every fusion/replacement attempt
//  of the conv/x_proj/dt slot regressed: R2 +36, R3 +85, R5 +165, R6 +130.)
// ---------------------------------------------------------------------------
__global__ void k_conv(const unsigned short* __restrict__ xm_bf, const float* __restrict__ cw,
                       const float* __restrict__ cb, unsigned short* __restrict__ xc_bf) {
    int idx = blockIdx.x * blockDim.x + threadIdx.x;
    if (idx >= NTOK * DI) return;
    int d = idx % DI;
    int bl = idx / DI;
    int l = bl % L;
    int b = bl / L;
    const unsigned short* base = xm_bf + (size_t)b * L * DI + d;
    float acc = cb[d];
#pragma unroll
    for (int k = 0; k < 4; k++) {
        int ll = l - 3 + k;
        if (ll >= 0) acc += bf2f(base[(size_t)ll * DI]) * cw[d * 4 + k];
    }
    xc_bf[idx] = f2bf(siluf(acc));
}

// ---------------------------------------------------------------------------
// K_dtpre: one block per token. dt = softplus(xdb_row . dtw_t + dtb) -> f32.
// ---------------------------------------------------------------------------
__global__ __launch_bounds__(384) void k_dtpre(
        const float* __restrict__ xdb, const float* __restrict__ dtw_t,
        const float* __restrict__ dtb, float* __restrict__ dtbuf) {
    int tok = blockIdx.x;
    int d = threadIdx.x;
    const float* xr = xdb + (size_t)tok * 44;
    float acc = dtb[d];
#pragma unroll
    for (int r = 0; r < R; r++) acc += xr[r] * dtw_t[r * DI + d];
    dtbuf[(size_t)tok * DI + d] = softplusf(acc);
}

// ---------------------------------------------------------------------------
// K4a: chunk-local scan; fast path: e1=exp(a0*dt) computed per step but
// issued right after the prefetched dt load -> hidden under h-chain.
// (depth-1 prefetch ON PURPOSE: depth-3 pipeline regressed +26 us, R12 --
//  dtbuf/xc are L2-resident, latency already covered; extra VALU hurt.)
// hend in [b][ch][n][d] layout. Writes packed ydt {y_local, dtcum}.
// LAST=true: only write ydt at t==P and chunk-last tokens.
// grid (NCH, BATCH) x 384 threads (d per thread).
// ---------------------------------------------------------------------------
template <bool LAST>
__global__ __launch_bounds__(384) void k_scanA(
        const unsigned short* __restrict__ xc_bf, const float* __restrict__ xdb,
        const float* __restrict__ dtbuf, const float* __restrict__ negA_l,
        const int* __restrict__ flag_l, const float* __restrict__ Dskip,
        float2* __restrict__ ydt, float* __restrict__ hend) {
    int d = threadIdx.x;
    int ch = blockIdx.x;
    int b = blockIdx.y;
    int t0 = ch * CH;
    int t1 = min(t0 + CH, L);
    bool fast = __all(flag_l[d] != 0);
    float a0 = negA_l[d];
    float a[S];
    if (!fast) {
#pragma unroll
        for (int n = 0; n < S; n++) a[n] = negA_l[n * DI + d];
    }
    float dsk = Dskip[d];
    float h[S] = {};
    float dts = 0.f;
    size_t tok0 = (size_t)b * L + t0;
    float dt_nx = dtbuf[tok0 * DI + d];
    float u_nx = bf2f(xc_bf[tok0 * DI + d]);
    float e1_nx = __expf(a0 * dt_nx);
    for (int t = t0; t < t1; t++) {
        size_t tok = (size_t)b * L + t;
        float dtv = dt_nx, e1v = e1_nx, uu = u_nx;
        if (t + 1 < t1) {  // prefetch + exp for next step, hidden by h-chain
            dt_nx = dtbuf[(tok + 1) * DI + d];
            u_nx = bf2f(xc_bf[(tok + 1) * DI + d]);
            e1_nx = __expf(a0 * dt_nx);
        }
        const float* row = xdb + tok * 44;   // block-uniform -> s_loads
        dts += dtv;
        float dtu = dtv * uu;
        float y = uu * dsk;
        if (fast) {
            float p = e1v;
#pragma unroll
            for (int n = 0; n < S; n++) {
                h[n] = p * h[n] + dtu * row[R + n];
                y += h[n] * row[R + S + n];
                p *= e1v;
            }
        } else {
#pragma unroll
            for (int n = 0; n < S; n++) {
                float dA = __expf(dtv * a[n]);
                h[n] = dA * h[n] + dtu * row[R + n];
                y += h[n] * row[R + S + n];
            }
        }
        if (!LAST || t == P || t == t1 - 1) ydt[tok * DI + d] = make_float2(y, dts);
    }
    float* he = hend + ((size_t)(b * NCH + ch) * S) * DI + d;
#pragma unroll
    for (int n = 0; n < S; n++) he[n * DI] = h[n];
}

// ---------------------------------------------------------------------------
// K4b: combine chunk prefixes serially (NCH chunks) -> h_init per chunk.
// ---------------------------------------------------------------------------
__global__ void k_scanB(const float* __restrict__ hend, const float2* __restrict__ ydt,
                        const float* __restrict__ negA_l, const int* __restrict__ flag_l,
                        float* __restrict__ hinit) {
    int idx = blockIdx.x * blockDim.x + threadIdx.x;
    if (idx >= BATCH * DI) return;
    int d = idx % DI;
    int b = idx / DI;
    bool fast = __all(flag_l[d] != 0);
    float a[S];
#pragma unroll
    for (int n = 0; n < S; n++) a[n] = negA_l[n * DI + d];
    float h[S] = {};
    for (int ch = 0; ch < NCH; ch++) {
        size_t o = ((size_t)(b * NCH + ch) * S) * DI + d;
#pragma unroll
        for (int n = 0; n < S; n++) hinit[o + n * DI] = h[n];
        int tlast = min(ch * CH + CH, L) - 1;
        float dts = ydt[((size_t)b * L + tlast) * DI + d].y;
        if (fast) {
            float e1c = __expf(a[0] * dts);
            float p = e1c;
#pragma unroll
            for (int n = 0; n < S; n++) {
                h[n] = p * h[n] + hend[o + n * DI];
                p *= e1c;
            }
        } else {
#pragma unroll
            for (int n = 0; n < S; n++) h[n] = __expf(dts * a[n]) * h[n] + hend[o + n * DI];
        }
    }
}

// ---------------------------------------------------------------------------
// K4c: fixup, one block per token: y = (y_local + sum_n c_n exp(a_n dtcum) h0_n)
//      * silu(z) -> bf16. cv row block-uniform; h0 coalesced; z from bf16.
// ---------------------------------------------------------------------------
__global__ __launch_bounds__(384) void k_fixup(
        const unsigned short* __restrict__ z_bf, const float* __restrict__ xdb,
        const float* __restrict__ negA_l, const int* __restrict__ flag_l,
        const float* __restrict__ hinit, const float2* __restrict__ ydt,
        unsigned short* __restrict__ y_bf) {
    int tok = blockIdx.x;
    int d = threadIdx.x;
    int l = tok % L;
    int b = tok / L;
    int ch = l / CH;
    size_t idx = (size_t)tok * DI + d;
    float2 yd = ydt[idx];
    float y = yd.x;
    if (ch != 0) {
        bool fast = __all(flag_l[d] != 0);
        const float* h0 = hinit + ((size_t)(b * NCH + ch) * S) * DI + d;
        const float* cv = xdb + (size_t)tok * 44 + R + S;  // block-uniform
        float dts = yd.y;
        float corr = 0.f;
        if (fast) {
            float e1c = __expf(negA_l[d] * dts);
            float p = e1c;
#pragma unroll
            for (int n = 0; n < S; n++) {
                corr += cv[n] * p * h0[n * DI];
                p *= e1c;
            }
        } else {
#pragma unroll
            for (int n = 0; n < S; n++)
                corr += cv[n] * __expf(negA_l[n * DI + d] * dts) * h0[n * DI];
        }
        y += corr;
    }
    float z = bf2f(z_bf[idx]);
    y_bf[idx] = f2bf(y * siluf(z));
}

// ---------------------------------------------------------------------------
// K4c-last: fixup only for the 32 cls tokens (b*L+P) -> compact y32 [b][d]
// ---------------------------------------------------------------------------
__global__ __launch_bounds__(384) void k_fixup_last(
        const unsigned short* __restrict__ z_bf, const float* __restrict__ xdb,
        const float* __restrict__ negA_l, const int* __restrict__ flag_l,
        const float* __restrict__ hinit, const float2* __restrict__ ydt,
        unsigned short* __restrict__ y32) {
    int b = blockIdx.x;
    int d = threadIdx.x;
    int tok = b * L + P;
    int ch = P / CH;   // last chunk
    size_t idx = (size_t)tok * DI + d;
    float2 yd = ydt[idx];
    float y = yd.x;
    {
        bool fast = __all(flag_l[d] != 0);
        const float* h0 = hinit + ((size_t)(b * NCH + ch) * S) * DI + d;
        const float* cv = xdb + (size_t)tok * 44 + R + S;
        float dts = yd.y;
        float corr = 0.f;
        if (fast) {
            float e1c = __expf(negA_l[d] * dts);
            float p = e1c;
#pragma unroll
            for (int n = 0; n < S; n++) {
                corr += cv[n] * p * h0[n * DI];
                p *= e1c;
            }
        } else {
#pragma unroll
            for (int n = 0; n < S; n++)
                corr += cv[n] * __expf(negA_l[n * DI + d] * dts) * h0[n * DI];
        }
        y += corr;
    }
    float z = bf2f(z_bf[idx]);
    y32[(size_t)b * DI + d] = f2bf(y * siluf(z));
}

// ---------------------------------------------------------------------------
// K5: final rmsnorm of token 400 of (resid+hidden32), then head matmul -> out
// ---------------------------------------------------------------------------
__global__ void k_head(const float* __restrict__ resid, const float* __restrict__ hidden32,
                       const float* __restrict__ norm_f_w, const float* __restrict__ head_w,
                       const float* __restrict__ head_b, float* __restrict__ out) {
    __shared__ float v[E];
    int b = blockIdx.x;
    int lane = threadIdx.x;
    size_t base = ((size_t)b * L + P) * E;
    float loc[3];
    float ss = 0.f;
#pragma unroll
    for (int j = 0; j < 3; j++) {
        int e = lane + j * 64;
        float x = resid[base + e] + hidden32[(size_t)b * E + e];
        loc[j] = x;
        ss += x * x;
    }
#pragma unroll
    for (int off = 32; off > 0; off >>= 1) ss += __shfl_xor(ss, off, 64);
    float scale = rsqrtf(ss * (1.f / (float)E) + 1e-5f);
#pragma unroll
    for (int j = 0; j < 3; j++) {
        int e = lane + j * 64;
        v[e] = loc[j] * scale * norm_f_w[e];
    }
    __syncthreads();
    if (lane < NC) {
        float acc = head_b[lane];
        for (int e = 0; e < E; e++) acc += v[e] * head_w[lane * E + e];
        out[b * NC + lane] = acc;
    }
}

// ---------------------------------------------------------------------------
extern "C" void kernel_launch(void* const* d_in, const int* in_sizes, int n_in,
                              void* d_out, int out_size, void* d_ws, size_t ws_size,
                              hipStream_t stream) {
    const float* imgs      = (const float*)d_in[0];
    const float* patch_w   = (const float*)d_in[1];
    const float* patch_b   = (const float*)d_in[2];
    const float* cls_token = (const float*)d_in[3];
    const float* pos_embed = (const float*)d_in[4];
    const float* cnn_w     = (const float*)d_in[5];
    const float* cnn_b     = (const float*)d_in[6];
    const float* norm_w    = (const float*)d_in[7];
    const float* in_proj_w = (const float*)d_in[8];
    const float* conv_w    = (const float*)d_in[9];
    const float* conv_b    = (const float*)d_in[10];
    const float* x_proj_w  = (const float*)d_in[11];
    const float* dt_proj_w = (const float*)d_in[12];
    const float* dt_proj_b = (const float*)d_in[13];
    const float* A_log     = (const float*)d_in[14];
    const float* Dskip     = (const float*)d_in[15];
    const float* out_proj_w= (const float*)d_in[16];
    const float* norm_f_w  = (const float*)d_in[17];
    const float* head_w    = (const float*)d_in[18];
    const float* head_b    = (const float*)d_in[19];

    float* ws = (float*)d_ws;
    size_t off = 0;
    float* resid  = ws + off; off += (size_t)NTOK * E;
    float* xdb    = ws + off; off += (size_t)NTOK * 44;
    float* dtbuf  = ws + off; off += (size_t)NTOK * DI;             // f32 dt only
    float* ydt    = ws + off; off += (size_t)NTOK * DI * 2;  // packed {y_local,dtcum}
    float* hend   = ws + off; off += (size_t)BATCH * NCH * DI * S;  // [b][ch][n][d]
    float* hinit  = ws + off; off += (size_t)BATCH * NCH * DI * S;  // [b][ch][n][d]
    float* negA   = ws + off; off += (size_t)DEPTH * DI * S;        // [layer][n][d]
    float* dtw_t  = ws + off; off += (size_t)DEPTH * DI * R;        // [layer][r][d]
    float* hid32  = ws + off; off += (size_t)BATCH * E;             // compact last hidden
    int*   gflag  = (int*)(ws + off); off += (size_t)DEPTH * DI;    // [layer][d]
    unsigned short* xm_bf  = (unsigned short*)(ws + off); off += (size_t)NTOK * DI / 2;
    unsigned short* z_bf   = (unsigned short*)(ws + off); off += (size_t)NTOK * DI / 2;
    unsigned short* bf_buf = (unsigned short*)(ws + off); off += (size_t)NTOK * DI / 2;
    unsigned short* y32_bf = (unsigned short*)(ws + off); off += (size_t)BATCH * DI / 2 + 16;
    unsigned short* w_in  = (unsigned short*)(ws + off); off += (size_t)DEPTH * 2 * DI * E / 2;
    unsigned short* w_x   = (unsigned short*)(ws + off); off += (size_t)DEPTH * 44 * DI / 2 + 16;
    unsigned short* w_out = (unsigned short*)(ws + off); off += (size_t)DEPTH * E * DI / 2;

    // shared bf16 buffer, disjoint live ranges:
    // hn_bf: rmsnorm -> in_proj; xc_bf: conv -> scanA; y_bf: fixup -> out_proj
    unsigned short* hn_bf = bf_buf;   // [NTOK, E]
    unsigned short* xc_bf = bf_buf;   // [NTOK, DI]
    unsigned short* y_bf  = bf_buf;   // [NTOK, DI]

    {
        int ntot = DEPTH * (2 * DI * E + 44 * DI + E * DI + DI * S + DI * R);
        k_prep<<<(ntot + 255) / 256, 256, 0, stream>>>(in_proj_w, x_proj_w, out_proj_w, A_log,
                                                       dt_proj_w, w_in, w_x, w_out, negA,
                                                       dtw_t);
        k_flag<<<(DEPTH * DI + 255) / 256, 256, 0, stream>>>(negA, gflag);
    }

    k_embed<<<(NTOK * E) / 256, 256, 0, stream>>>(imgs, patch_w, patch_b, cls_token,
                                                  pos_embed, cnn_w, cnn_b, resid);

    for (int i = 0; i < DEPTH; i++) {
        // hn = rmsnorm(resid)*w  (resid already includes all prior hiddens)
        k_rmsnorm<<<NTOK / 4, 256, 0, stream>>>(resid, hn_bf, norm_w + i * E);

        // in_proj: [NTOK,192]bf16 x [768,192]bf16^T -> split: xm bf16 + z bf16
        // BK=64 kept: grid 4.7 blocks/CU, BK=96 would cut LDS capacity 5->4.
        {
            dim3 g((2 * DI) / 64, (NTOK + 127) / 128);
            k_gemm_bf16<128, 64, 64, 1><<<g, 256, 0, stream>>>(
                hn_bf, w_in + (size_t)i * 2 * DI * E, nullptr, xm_bf, z_bf, NTOK, 2 * DI, E);
        }
        // causal conv4 + silu -> xc_bf
        k_conv<<<(NTOK * DI) / 256, 256, 0, stream>>>(xm_bf, conv_w + (size_t)i * DI * 4,
                                                      conv_b + (size_t)i * DI, xc_bf);
        // x_proj: [NTOK,384]bf16 x [44,384]bf16^T -> xdb f32 [NTOK,44]
        // BK=128: 3 K-iters instead of 6 (bit-identical accumulation order).
        {
            dim3 g(1, NTOK / 32);
            k_gemm_bf16<32, 64, 128, 0><<<g, 256, 0, stream>>>(
                xc_bf, w_x + (size_t)i * 44 * DI, xdb, nullptr, nullptr, NTOK, 44, DI);
        }
        const float* nA = negA + (size_t)i * DI * S;
        const int* fl = gflag + (size_t)i * DI;
        // dt_proj + softplus -> f32 dt (block per token, throughput-parallel)
        k_dtpre<<<NTOK, 384, 0, stream>>>(xdb, dtw_t + (size_t)i * DI * R,
                                          dt_proj_b + (size_t)i * DI, dtbuf);
        // chunked scan: local scan -> chunk combine -> parallel fixup
        dim3 g(NCH, BATCH);
        if (i < DEPTH - 1) {
            k_scanA<false><<<g, DI, 0, stream>>>(xc_bf, xdb, dtbuf, nA, fl,
                                                 Dskip + (size_t)i * DI, (float2*)ydt, hend);
            k_scanB<<<(BATCH * DI + 255) / 256, 256, 0, stream>>>(hend, (const float2*)ydt,
                                                                  nA, fl, hinit);
            k_fixup<<<NTOK, 384, 0, stream>>>(z_bf, xdb, nA, fl, hinit,
                                              (const float2*)ydt, y_bf);
            // out_proj + residual accumulate: resid += y_bf @ w_out^T
            // BK=128: 3 K-iters instead of 6 (bit-identical).
            dim3 go(E / 64, (NTOK + 63) / 64);
            k_gemm_bf16<64, 64, 128, 2><<<go, 256, 0, stream>>>(
                y_bf, w_out + (size_t)i * E * DI, resid, nullptr, nullptr, NTOK, E, DI);
        } else {
            // last layer: only the cls token (P) of each batch feeds the head
            k_scanA<true><<<g, DI, 0, stream>>>(xc_bf, xdb, dtbuf, nA, fl,
                                                Dskip + (size_t)i * DI, (float2*)ydt, hend);
            k_scanB<<<(BATCH * DI + 255) / 256, 256, 0, stream>>>(hend, (const float2*)ydt,
                                                                  nA, fl, hinit);
            k_fixup_last<<<BATCH, 384, 0, stream>>>(z_bf, xdb, nA, fl, hinit,
                                                    (const float2*)ydt, y32_bf);
            // out_proj on 32 rows only: [32,384] x [192,384]^T -> hid32 [32,192]
            dim3 go(E / 64, 1);
            k_gemm_bf16<32, 64, 128, 0><<<go, 256, 0, stream>>>(
                y32_bf, w_out + (size_t)i * E * DI, hid32, nullptr, nullptr, BATCH, E, DI);
        }
    }

    k_head<<<BATCH, 64, 0, stream>>>(resid, hid32, norm_f_w, head_w, head_b, (float*)d_out);
}